// Round 13
// baseline (172.583 us; speedup 1.0000x reference)
//
#include <hip/hip_runtime.h>
#include <stdint.h>

#define IN_DIM 1024
#define H_DIM  1024
#define BATCH  8192
#define KDIM   2048   // IN + H
#define NDIM   4096   // 4*H
#define BM     128
#define BN     256
#define BK     32
#define NT     (KDIM / BK)   // 64 K-tiles

typedef __bf16 bf16x8 __attribute__((ext_vector_type(8)));
typedef float  f32x4  __attribute__((ext_vector_type(4)));
typedef unsigned int u32;

static __device__ __forceinline__ unsigned short f2bf(float f) {
  u32 u = __builtin_bit_cast(u32, f);
  u += 0x7FFFu + ((u >> 16) & 1u);   // round-to-nearest-even
  return (unsigned short)(u >> 16);
}

static __device__ __forceinline__ float sigm(float x) {
  return 1.0f / (1.0f + __expf(-x));
}
static __device__ __forceinline__ float tanh_fast(float x) {
  float e = __expf(-2.0f * fabsf(x));     // in (0,1], no overflow
  float t = (1.0f - e) / (1.0f + e);
  return copysignf(t, x);
}

// ---- fused prep: one dispatch does A-convert, Bt-permute, bias (R12) ----
__global__ void prep_all(const float* __restrict__ x, const float* __restrict__ h,
                         const float* __restrict__ Wi, const float* __restrict__ Wh,
                         const float* __restrict__ bi, const float* __restrict__ bh,
                         unsigned short* __restrict__ A,
                         unsigned short* __restrict__ Bt,
                         float* __restrict__ bias) {
  __shared__ float tile[32][33];
  const int b = blockIdx.x;
  const int t = threadIdx.x;

  if (b < 2048) {
    const int total = BATCH * KDIM / 4;
    for (int i = b * 256 + t; i < total; i += 2048 * 256) {
      int bb = i >> 9;             // 512 quads per row
      int k = (i & 511) << 2;
      const float* src = (k < IN_DIM) ? (x + (size_t)bb * IN_DIM + k)
                                      : (h + (size_t)bb * H_DIM + (k - IN_DIM));
      float4 v = *reinterpret_cast<const float4*>(src);
      ushort4 o;
      o.x = f2bf(v.x); o.y = f2bf(v.y); o.z = f2bf(v.z); o.w = f2bf(v.w);
      *reinterpret_cast<ushort4*>(A + (size_t)bb * KDIM + k) = o;
    }
  } else if (b < 10240) {
    int bb = b - 2048;
    int k0 = (bb & 63) * 32;           // k of combined [Wi;Wh]
    int c0 = (bb >> 6) * 32;           // orig col
    int tx = t & 31;
    int ty = t >> 5;                   // 0..7
    const float* src = (k0 < IN_DIM) ? (Wi + (size_t)k0 * NDIM)
                                     : (Wh + (size_t)(k0 - IN_DIM) * NDIM);
    for (int i = 0; i < 4; i++) {
      int r = ty + 8 * i;
      tile[r][tx] = src[(size_t)r * NDIM + c0 + tx];
    }
    __syncthreads();
    int g = c0 >> 10;                  // gate index (tile doesn't straddle)
    int ubase = c0 & 1023;
    for (int i = 0; i < 4; i++) {
      int cc = ty + 8 * i;
      int u = ubase + cc;
      int j = ((u >> 4) << 6) + (g << 4) + (u & 15);
      Bt[(size_t)j * KDIM + k0 + tx] = f2bf(tile[tx][cc]);
    }
  } else {
    int j = (b - 10240) * 256 + t;     // < 4096
    int u = ((j >> 6) << 4) + (j & 15);
    int g = (j >> 4) & 3;
    int c = (g << 10) + u;
    bias[j] = bi[c] + bh[c];
  }
}

// --- 128x256 GEMM, BK=32, 256 thr, 2-barrier/K-tile, 2+ blocks/CU (R13) ---
static __device__ __forceinline__ void gload_lds16(const void* g, void* l) {
  __builtin_amdgcn_global_load_lds(
      (const __attribute__((address_space(1))) u32*)g,
      (__attribute__((address_space(3))) u32*)l, 16, 0, 0);
}

#define MFMA __builtin_amdgcn_mfma_f32_16x16x32_bf16
#define SGB  __builtin_amdgcn_sched_group_barrier
// LLVM SchedGroupMask: MFMA=0x8, DS_READ=0x100

__launch_bounds__(256, 2)
__global__ void lstm_gemm(const unsigned short* __restrict__ A,
                          const unsigned short* __restrict__ Bt,
                          const float* __restrict__ bias,
                          const float* __restrict__ Cin,
                          float* __restrict__ Hout,
                          float* __restrict__ Cout) {
  // LDS: A [2 buf][128 rows][64B] = 16K | B [2 buf][256 rows][64B] = 32K
  __shared__ __align__(16) char smem[49152];

  const int t  = threadIdx.x;
  const int l  = t & 63;
  const int w  = t >> 6;           // wave 0-3
  const int lane16 = l & 15;
  const int kg = l >> 4;           // 0-3
  const int wc = w;                // N-position

  int bid = blockIdx.x;            // 1024 blocks (64 M-tiles x 16 N-tiles)
  int swz = (bid & 7) * 128 + (bid >> 3);  // bijective XCD swizzle (1024%8==0)
  int tile_m = swz >> 4;           // 0..63
  int tile_n = swz & 15;           // 0..15
  int brow = tile_m * BM;
  int bRowB = tile_n * BN;         // Bt row base (gate-cols)

  // ---- staging: per GL call q, thread t writes LDS linear (q*4096 + t*16);
  //      row = q*64 + w*16 + (l>>2); global chunk pre-swizzled
  //      c = (l&3) ^ ((l>>3)&3)  == chunk ^ ((row>>1)&3)  (same involution
  //      as the read side, both reduce row-dependence to (row>>1)&3) ----
  const int cth = (l & 3) ^ ((l >> 3) & 3);
  const int srow = w * 16 + (l >> 2);
  const unsigned short* aq0 = A + (size_t)(brow + srow) * KDIM + cth * 8;
  const unsigned short* aq1 = aq0 + (size_t)64 * KDIM;
  const unsigned short* bq0 = Bt + (size_t)(bRowB + srow) * KDIM + cth * 8;
  const unsigned short* bq1 = bq0 + (size_t)64 * KDIM;
  const unsigned short* bq2 = bq0 + (size_t)128 * KDIM;
  const unsigned short* bq3 = bq0 + (size_t)192 * KDIM;

#define GL(gp, loff) gload_lds16((gp), smem + (loff) + w * 1024 + l * 16)

  // ---- per-lane ds_read bases (chunk ^= (row>>1)&3, row≡lane16 mod 16) ----
  const int rsw = ((kg ^ ((lane16 >> 1) & 3)) << 4);
  char* vRA = smem + lane16 * 64 + rsw;            // A(P,m) = +P*8192 + m*1024
  char* vRB = smem + 16384 + wc * 4096 + lane16 * 64 + rsw; // B(P,n)=+P*16384+n*1024

  f32x4 acc[8][4];
#pragma unroll
  for (int m = 0; m < 8; m++)
#pragma unroll
    for (int n = 0; n < 4; n++) acc[m][n] = (f32x4){0.f, 0.f, 0.f, 0.f};

  // ---- prologue: B(0),A(0) -> buf0 ; B(1) -> buf1 ; [A(1) after barrier] ----
  GL(bq0, 16384);          GL(bq1, 16384 + 4096);
  GL(bq2, 16384 + 8192);   GL(bq3, 16384 + 12288);
  GL(aq0, 0);              GL(aq1, 4096);
  GL(bq0 + 32, 32768);         GL(bq1 + 32, 32768 + 4096);
  GL(bq2 + 32, 32768 + 8192);  GL(bq3 + 32, 32768 + 12288);
  asm volatile("s_waitcnt vmcnt(4)" ::: "memory");   // tile0 landed
  __builtin_amdgcn_s_barrier();
  __builtin_amdgcn_sched_barrier(0);
  GL(aq0 + 32, 8192);      GL(aq1 + 32, 8192 + 4096);   // A(1) -> buf1

  // ---- operand registers (rotation lifetimes disjoint, R9 pattern) ----
  bf16x8 afrA[4], afrB[4], bfrX[2], bfrY[2];
#pragma unroll
  for (int mm = 0; mm < 4; mm++)
    afrA[mm] = *(const bf16x8*)(vRA + mm * 1024);
#pragma unroll
  for (int nn = 0; nn < 2; nn++)
    bfrX[nn] = *(const bf16x8*)(vRB + nn * 1024);
  // roll pointers to tile 2 (stage distance 2)
  aq0 += 64; aq1 += 64; bq0 += 64; bq1 += 64; bq2 += 64; bq3 += 64;

  // ---- 2-barrier K-tile body. vmcnt induction (FIFO): at gate(t) the
  //      outstanding tail is [B(t+1)x4, A(t+1)x2, B(t+2)x4] -> vmcnt(4)
  //      drains tile t+1 exactly. Region WAR: S_B after bar_A (B(t) readers:
  //      Q4(t-1)/Q1(t), >=1 barrier — R9-verified pattern); S_A after bar_B
  //      (A(t) m4-7 read in Q2(t), bar_B between). sched_barrier(0) after
  //      each barrier stops GL/ds_read hoisting (rule #18).
#define BODY(P)                                                              \
  {                                                                          \
    /* Q1: MFMA acc[0..3][0,1] = afrA x bfrX ∥ read bfrY = B n2,n3 (t) */    \
    __builtin_amdgcn_s_setprio(1);                                           \
    _Pragma("unroll") for (int nn = 0; nn < 2; nn++)                         \
      bfrY[nn] = *(const bf16x8*)(vRB + (P)*16384 + (2+nn)*1024);            \
    _Pragma("unroll") for (int mm = 0; mm < 4; mm++)                         \
      _Pragma("unroll") for (int nn = 0; nn < 2; nn++)                       \
        acc[mm][nn] = MFMA(afrA[mm], bfrX[nn], acc[mm][nn], 0, 0, 0);        \
    SGB(0x100, 1, 0); SGB(0x8, 4, 0);                                        \
    SGB(0x100, 1, 0); SGB(0x8, 4, 0);                                        \
    __builtin_amdgcn_s_setprio(0);                                           \
    __builtin_amdgcn_s_barrier();          /* bar_A */                       \
    __builtin_amdgcn_sched_barrier(0);                                       \
    /* S_B: stage B(t+2) -> buf P */                                         \
    GL(bq0, 16384 + (P)*16384);                                              \
    GL(bq1, 16384 + (P)*16384 + 4096);                                       \
    GL(bq2, 16384 + (P)*16384 + 8192);                                       \
    GL(bq3, 16384 + (P)*16384 + 12288);                                      \
    /* Q2: MFMA acc[0..3][2,3] = afrA x bfrY ∥ read afrB = A m4..7 (t) */    \
    __builtin_amdgcn_s_setprio(1);                                           \
    _Pragma("unroll") for (int mm = 0; mm < 4; mm++)                         \
      afrB[mm] = *(const bf16x8*)(vRA + (P)*8192 + (4+mm)*1024);             \
    _Pragma("unroll") for (int mm = 0; mm < 4; mm++)                         \
      _Pragma("unroll") for (int nn = 2; nn < 4; nn++)                       \
        acc[mm][nn] = MFMA(afrA[mm], bfrY[nn-2], acc[mm][nn], 0, 0, 0);      \
    SGB(0x100, 1, 0); SGB(0x8, 2, 0);                                        \
    SGB(0x100, 1, 0); SGB(0x8, 2, 0);                                        \
    SGB(0x100, 1, 0); SGB(0x8, 2, 0);                                        \
    SGB(0x100, 1, 0); SGB(0x8, 2, 0);                                        \
    __builtin_amdgcn_s_setprio(0);                                           \
    /* Q3: MFMA acc[4..7][0,1] = afrB x bfrX (register-only) */              \
    __builtin_amdgcn_s_setprio(1);                                           \
    _Pragma("unroll") for (int mm = 0; mm < 4; mm++)                         \
      _Pragma("unroll") for (int nn = 0; nn < 2; nn++)                       \
        acc[4+mm][nn] = MFMA(afrB[mm], bfrX[nn], acc[4+mm][nn], 0, 0, 0);    \
    __builtin_amdgcn_s_setprio(0);                                           \
    /* gate: drain tile t+1 (leave B(t+2)x4 in flight) */                    \
    asm volatile("s_waitcnt vmcnt(4)" ::: "memory");                         \
    __builtin_amdgcn_s_barrier();          /* bar_B */                       \
    __builtin_amdgcn_sched_barrier(0);                                       \
    /* S_A: stage A(t+2) -> buf P (A(t) readers drained pre-bar_B) */        \
    GL(aq0, (P)*8192);                                                       \
    GL(aq1, (P)*8192 + 4096);                                                \
    /* Q4: MFMA acc[4..7][2,3] = afrB x bfrY ∥ read afrA,bfrX of t+1 */      \
    __builtin_amdgcn_s_setprio(1);                                           \
    _Pragma("unroll") for (int mm = 0; mm < 4; mm++)                         \
      afrA[mm] = *(const bf16x8*)(vRA + ((P)^1)*8192 + mm*1024);             \
    _Pragma("unroll") for (int nn = 0; nn < 2; nn++)                         \
      bfrX[nn] = *(const bf16x8*)(vRB + ((P)^1)*16384 + nn*1024);            \
    _Pragma("unroll") for (int mm = 0; mm < 4; mm++)                         \
      _Pragma("unroll") for (int nn = 2; nn < 4; nn++)                       \
        acc[4+mm][nn] = MFMA(afrB[mm], bfrY[nn-2], acc[4+mm][nn], 0, 0, 0);  \
    SGB(0x100, 3, 0); SGB(0x8, 4, 0);                                        \
    SGB(0x100, 3, 0); SGB(0x8, 4, 0);                                        \
    __builtin_amdgcn_s_setprio(0);                                           \
    aq0 += 32; aq1 += 32; bq0 += 32; bq1 += 32; bq2 += 32; bq3 += 32;        \
  }

  for (int it = 0; it < NT / 2; ++it) {
    BODY(0)
    BODY(1)
  }
#undef BODY
#undef GL

  // ---- drain outstanding staging loads (also orders Cin/bias below) ----
  asm volatile("s_waitcnt vmcnt(0)" ::: "memory");

  // ---- epilogue: register-only gates (lane owns all 4 gates of unit U) ----
  const int U = tile_n * 64 + wc * 16 + lane16;
  const float* cinp = Cin + (size_t)(brow + kg * 4) * H_DIM + U;
  float cin[32];
#pragma unroll
  for (int m = 0; m < 8; m++)
#pragma unroll
    for (int r = 0; r < 4; r++)
      cin[m * 4 + r] = cinp[(size_t)(m * 16 + r) * H_DIM];
  float bv[4];
#pragma unroll
  for (int nn = 0; nn < 4; nn++)
    bv[nn] = bias[tile_n * 256 + wc * 64 + nn * 16 + lane16];

  float* hp = Hout + (size_t)(brow + kg * 4) * H_DIM + U;
  float* cp = Cout + (size_t)(brow + kg * 4) * H_DIM + U;
#pragma unroll
  for (int m = 0; m < 8; m++)
#pragma unroll
    for (int r = 0; r < 4; r++) {
      float Ig = sigm(acc[m][0][r] + bv[0]);
      float Fg = sigm(acc[m][1][r] + bv[1]);
      float Gg = tanh_fast(acc[m][2][r] + bv[2]);
      float Og = sigm(acc[m][3][r] + bv[3]);
      float cn = Fg * cin[m * 4 + r] + Ig * Gg;
      size_t off = (size_t)(m * 16 + r) * H_DIM;
      hp[off] = Og * tanh_fast(cn);
      cp[off] = cn;
    }
}

extern "C" void kernel_launch(void* const* d_in, const int* in_sizes, int n_in,
                              void* d_out, int out_size, void* d_ws, size_t ws_size,
                              hipStream_t stream) {
  const float* x  = (const float*)d_in[0];
  const float* h  = (const float*)d_in[1];
  const float* c  = (const float*)d_in[2];
  const float* Wi = (const float*)d_in[3];
  const float* bi = (const float*)d_in[4];
  const float* Wh = (const float*)d_in[5];
  const float* bh = (const float*)d_in[6];

  float* out  = (float*)d_out;
  float* Hout = out;
  float* Cout = out + (size_t)BATCH * H_DIM;

  // workspace layout: A bf16 (32 MiB) | Bt bf16 (16 MiB) | bias f32 (16 KiB)
  unsigned short* Abf = (unsigned short*)d_ws;
  unsigned short* Btb = (unsigned short*)((char*)d_ws + 33554432);
  float*          bsf = (float*)((char*)d_ws + 50331648);

  prep_all<<<10256, 256, 0, stream>>>(x, h, Wi, Wh, bi, bh, Abf, Btb, bsf);
  lstm_gemm<<<1024, 256, 0, stream>>>(Abf, Btb, bsf, c, Hout, Cout);
}